// Round 14
// baseline (156.913 us; speedup 1.0000x reference)
//
#include <hip/hip_runtime.h>
#include <math.h>

namespace {
constexpr int B = 8, L = 512, E = 512, H = 8;
constexpr int M = B * L;  // 4096
}

typedef float f32x4 __attribute__((ext_vector_type(4)));
typedef short bf16x8 __attribute__((ext_vector_type(8)));

__device__ inline ushort f2b(float f) {
  unsigned u = __float_as_uint(f);
  u += 0x7FFF + ((u >> 16) & 1);
  return (ushort)(u >> 16);
}
__device__ inline float b2f(ushort h) { return __uint_as_float(((unsigned)h) << 16); }

__device__ inline f32x4 mfma16(bf16x8 a, bf16x8 b, f32x4 c) {
  return __builtin_amdgcn_mfma_f32_16x16x32_bf16(a, b, c, 0, 0, 0);
}

// async global->LDS 16B per lane (LDS dest = wave-uniform base + lane*16)
__device__ __forceinline__ void gl2lds16(const ushort* g, ushort* l) {
  __builtin_amdgcn_global_load_lds(
      (const __attribute__((address_space(1))) void*)g,
      (__attribute__((address_space(3))) void*)l, 16, 0, 0);
}

// Stage NROWS x 64 bf16 tile into linear LDS [row][64] with inverse-XOR-swizzled
// SOURCE: LDS slot s of row r holds global chunk s^(r&7).
template <int NROWS>
__device__ __forceinline__ void stage64(const ushort* __restrict__ g, int ldg,
                                        ushort* lds, int tid) {
  const int w = tid >> 6, l = tid & 63;
  constexpr int RPW = NROWS / 4;
  constexpr int NI = RPW / 8;
#pragma unroll
  for (int it = 0; it < NI; ++it) {
    const int rbase = w * RPW + it * 8;
    const int row = rbase + (l >> 3);
    const int chunk = (l & 7) ^ (row & 7);
    gl2lds16(g + (size_t)row * ldg + chunk * 8, lds + rbase * 64);
  }
}

// reg-staged f32 -> bf16 convert into swizzled LDS tile (Af pre-offset).
template <int BM>
__device__ __forceinline__ void stage_f32(const float* __restrict__ Af, int ldA,
                                          ushort* dst, int tid) {
#pragma unroll
  for (int it = 0; it < BM / 32; ++it) {
    const int row = (tid >> 3) + it * 32;
    const int slot = tid & 7;
    const float* src = Af + (size_t)row * ldA + slot * 8;
    float4 v0 = *(const float4*)src;
    float4 v1 = *(const float4*)(src + 4);
    union { uint4 u; ushort s[8]; } vo;
    vo.s[0] = f2b(v0.x); vo.s[1] = f2b(v0.y);
    vo.s[2] = f2b(v0.z); vo.s[3] = f2b(v0.w);
    vo.s[4] = f2b(v1.x); vo.s[5] = f2b(v1.y);
    vo.s[6] = f2b(v1.z); vo.s[7] = f2b(v1.w);
    *(uint4*)(&dst[row * 64 + ((slot ^ (row & 7)) * 8)]) = vo.u;
  }
}

// reg-staged combine of bf16 buffers (row stride 512) into swizzled LDS tile.
// NBUF=2: b0+b1.  NBUF=4: (b0+b1)+relu(b2+b3).
template <int BM, int NBUF>
__device__ __forceinline__ void stage_comb(const ushort* b0, const ushort* b1,
                                           const ushort* b2, const ushort* b3,
                                           ushort* lds, int tid) {
#pragma unroll
  for (int it = 0; it < BM / 32; ++it) {
    const int row = (tid >> 3) + it * 32;
    const int slot = tid & 7;
    const size_t off = (size_t)row * 512 + slot * 8;
    union Uu { uint4 u; ushort s[8]; } va, vb, vc, vd, vo;
    va.u = *(const uint4*)(b0 + off);
    vb.u = *(const uint4*)(b1 + off);
    if (NBUF == 4) {
      vc.u = *(const uint4*)(b2 + off);
      vd.u = *(const uint4*)(b3 + off);
    }
#pragma unroll
    for (int e = 0; e < 8; ++e) {
      float f = b2f(va.s[e]) + b2f(vb.s[e]);
      if (NBUF == 4) f += fmaxf(b2f(vc.s[e]) + b2f(vd.s[e]), 0.f);
      vo.s[e] = f2b(f);
    }
    *(uint4*)(&lds[row * 64 + ((slot ^ (row & 7)) * 8)]) = vo.u;
  }
}

// ------------- 2-phase double-buffered MFMA GEMM core -----------------------
// A:(rows x K) bf16 rm (f32 when STAGEA==1), Wt:(N x K) bf16 rm. BK=64.
// MODE 1: C0 (rows x N).  MODE 5: 2 secs k(C1)|v(C2 transposed (B,E,L)).
// MODE 4: split-A f1 (K-tiles 0..7 comb4, 8..15 from Aq).
// STAGEA 0: gl2lds. 1: f32 reg-convert. 2: comb2(A,A2).
//        5: t<8 comb4(A,A2,A3,A4), t>=8 f32 reg-convert from Aq.
// FUSE 1: epilogue = atomic dot with w2 into outv (instead of C store).
template <int BM, int MODE, int HAS_BIAS, int ACT, int STAGEA, int FUSE>
__device__ __forceinline__ void dev_gemm(
    ushort* lds, int bxx, int by, const ushort* A, const ushort* A2,
    const ushort* A3, const ushort* A4, const ushort* Aq,
    const ushort* Wt, const float* bias, ushort* C0, ushort* C1, ushort* C2,
    const float* w2, float* outv, int K, int N) {
  ushort* Als = lds;
  ushort* Bls = lds + 2 * BM * 64;
  const int tid = threadIdx.x;
  const int l = tid & 63, wv = tid >> 6;
  const int wr = wv >> 1, wc = wv & 1;
  const int g = l >> 4, c = l & 15;
  constexpr int WM = BM / 2;
  constexpr int MFR = WM / 16;
  const int bm = by * BM;
  const int bn64 = bxx * 64;
  const int sec = (MODE == 5) ? (bn64 >> 9) : 0;
  const bool vsec = (MODE == 5 && sec == 1);

  const ushort* Ause = (MODE == 5) ? A2 : A;
  const int ldA = K;
  const ushort* Bp = Wt + (size_t)bn64 * K;

  f32x4 acc[MFR][2];
#pragma unroll
  for (int mi = 0; mi < MFR; ++mi)
#pragma unroll
    for (int ni = 0; ni < 2; ++ni) acc[mi][ni] = f32x4{0.f, 0.f, 0.f, 0.f};

  auto stageA = [&](int t, int buf) {
    ushort* dst = Als + buf * BM * 64;
    if (STAGEA == 0) {
      stage64<BM>(Ause + (size_t)bm * ldA + t * 64, ldA, dst, tid);
    } else if (STAGEA == 1) {
      stage_f32<BM>((const float*)A + (size_t)bm * ldA + t * 64, ldA, dst, tid);
    } else if (STAGEA == 2) {
      stage_comb<BM, 2>(A + (size_t)bm * 512 + t * 64,
                        A2 + (size_t)bm * 512 + t * 64, nullptr, nullptr, dst, tid);
    } else {  // STAGEA == 5
      if (t < 8)
        stage_comb<BM, 4>(A + (size_t)bm * 512 + t * 64,
                          A2 + (size_t)bm * 512 + t * 64,
                          A3 + (size_t)bm * 512 + t * 64,
                          A4 + (size_t)bm * 512 + t * 64, dst, tid);
      else
        stage_f32<BM>((const float*)Aq + (size_t)bm * 512 + (t - 8) * 64, 512,
                      dst, tid);
    }
  };

  stageA(0, 0);
  stage64<64>(Bp, K, Bls, tid);
  __syncthreads();

  const int NT = K >> 6;
  int cur = 0;
  for (int t = 0; t < NT; ++t) {
    if (t + 1 < NT) {
      stageA(t + 1, cur ^ 1);
      stage64<64>(Bp + (t + 1) * 64, K, Bls + (cur ^ 1) * 64 * 64, tid);
    }
#pragma unroll
    for (int ks = 0; ks < 2; ++ks) {
      bf16x8 af[MFR], bf_[2];
#pragma unroll
      for (int mi = 0; mi < MFR; ++mi) {
        const int row = wr * WM + mi * 16 + c;
        af[mi] = *(const bf16x8*)(&Als[cur * BM * 64 + row * 64 +
                                       (((ks * 4 + g) ^ (row & 7)) * 8)]);
      }
#pragma unroll
      for (int ni = 0; ni < 2; ++ni) {
        const int row = wc * 32 + ni * 16 + c;
        bf_[ni] = *(const bf16x8*)(&Bls[cur * 64 * 64 + row * 64 +
                                        (((ks * 4 + g) ^ (row & 7)) * 8)]);
      }
      if (vsec) {
#pragma unroll
        for (int mi = 0; mi < MFR; ++mi)
#pragma unroll
          for (int ni = 0; ni < 2; ++ni)
            acc[mi][ni] = mfma16(bf_[ni], af[mi], acc[mi][ni]);
      } else {
#pragma unroll
        for (int mi = 0; mi < MFR; ++mi)
#pragma unroll
          for (int ni = 0; ni < 2; ++ni)
            acc[mi][ni] = mfma16(af[mi], bf_[ni], acc[mi][ni]);
      }
    }
    __syncthreads();
    cur ^= 1;
  }

  if (FUSE) {
    // out[m] += sum_n relu(acc + bf1[n]) * w2[n]; out pre-init'd to bf2.
    float w2v[2];
#pragma unroll
    for (int ni = 0; ni < 2; ++ni) w2v[ni] = w2[bn64 + wc * 32 + ni * 16 + c];
#pragma unroll
    for (int mi = 0; mi < MFR; ++mi) {
#pragma unroll
      for (int r = 0; r < 4; ++r) {
        float p = 0.f;
#pragma unroll
        for (int ni = 0; ni < 2; ++ni) {
          const int n = bn64 + wc * 32 + ni * 16 + c;
          float v = acc[mi][ni][r] + bias[n];
          v = fmaxf(v, 0.f);
          p += v * w2v[ni];
        }
        p += __shfl_xor(p, 1);
        p += __shfl_xor(p, 2);
        p += __shfl_xor(p, 4);
        p += __shfl_xor(p, 8);
        if (c == 0) atomicAdd(&outv[bm + wr * WM + mi * 16 + g * 4 + r], p);
      }
    }
  } else if (vsec) {
    // swapped acc: D rows = E-dim, cols = tokens -> vt (B,E,L)
    const int e0 = bn64 - 512;
#pragma unroll
    for (int ni = 0; ni < 2; ++ni) {
#pragma unroll
      for (int r = 0; r < 4; ++r) {
        const int e = e0 + wc * 32 + ni * 16 + g * 4 + r;
        const float bv = HAS_BIAS ? bias[512 + e] : 0.f;
#pragma unroll
        for (int mi = 0; mi < MFR; ++mi) {
          const int m = bm + wr * WM + mi * 16 + c;
          const int bb = m >> 9, lt = m & 511;
          C2[((size_t)bb * 512 + e) * 512 + lt] = f2b(acc[mi][ni][r] + bv);
        }
      }
    }
  } else {
    ushort* dst = (MODE == 5) ? C1 : C0;
    const int nsub = (MODE == 5) ? sec * 512 : 0;
    const int ldc = (MODE == 5) ? 512 : N;
#pragma unroll
    for (int ni = 0; ni < 2; ++ni) {
      const int n = bn64 + wc * 32 + ni * 16 + c;
      const float bv = HAS_BIAS ? bias[n] : 0.f;
#pragma unroll
      for (int mi = 0; mi < MFR; ++mi) {
#pragma unroll
        for (int r = 0; r < 4; ++r) {
          const int m = bm + wr * WM + mi * 16 + g * 4 + r;
          float v = acc[mi][ni][r] + bv;
          if (ACT) v = fmaxf(v, 0.f);
          dst[(size_t)m * ldc + (n - nsub)] = f2b(v);
        }
      }
    }
  }
}

// ---------------- attention core: aexp = (c_p/l) * sum exp(QK^T/8) V --------
__device__ __forceinline__ void dev_attn(ushort* lds, int qt, int h, int b,
                                         const ushort* __restrict__ Qg,
                                         const ushort* __restrict__ Kg,
                                         const ushort* __restrict__ Vt,
                                         float c_p, ushort* __restrict__ aexp) {
  ushort* Qs = lds;           // 4096
  ushort* Ps = lds + 4096;    // 4096
  ushort* Ks = lds + 8192;    // 2 x 4096
  ushort* Vs = lds + 16384;   // 2 x 4096
  const int tid = threadIdx.x, l = tid & 63, w = tid >> 6;
  const int g = l >> 4, c = l & 15;
  const int qrow0 = b * L + qt * 64;
  const ushort* Kbase = Kg + (size_t)(b * L) * E + h * 64;
  const ushort* Vbase = Vt + (size_t)(b * E + h * 64) * L;

  stage64<64>(Qg + (size_t)qrow0 * E + h * 64, E, Qs, tid);
  stage64<64>(Kbase, E, Ks, tid);
  stage64<64>(Vbase, L, Vs, tid);
  __syncthreads();

  f32x4 o[4];
#pragma unroll
  for (int dn = 0; dn < 4; ++dn) o[dn] = f32x4{0.f, 0.f, 0.f, 0.f};
  float l_r[4] = {0.f, 0.f, 0.f, 0.f};

  int cur = 0;
  for (int kt = 0; kt <= qt; ++kt) {
    if (kt < qt) {
      stage64<64>(Kbase + (size_t)(kt + 1) * 64 * E, E, Ks + (cur ^ 1) * 4096, tid);
      stage64<64>(Vbase + (kt + 1) * 64, L, Vs + (cur ^ 1) * 4096, tid);
    }
    bf16x8 qf[2];
#pragma unroll
    for (int kq = 0; kq < 2; ++kq) {
      int row = w * 16 + c;
      qf[kq] = *(const bf16x8*)(&Qs[row * 64 + (((kq * 4 + g) ^ (row & 7)) * 8)]);
    }
    f32x4 s4[4];
#pragma unroll
    for (int n = 0; n < 4; ++n) s4[n] = f32x4{0.f, 0.f, 0.f, 0.f};
#pragma unroll
    for (int n = 0; n < 4; ++n) {
#pragma unroll
      for (int kq = 0; kq < 2; ++kq) {
        int row = n * 16 + c;
        bf16x8 kf = *(const bf16x8*)(&Ks[cur * 4096 + row * 64 +
                                         (((kq * 4 + g) ^ (row & 7)) * 8)]);
        s4[n] = mfma16(qf[kq], kf, s4[n]);
      }
    }
    // P = exp(S/8), no max subtraction (|S/8| bounded; masked -> 0)
    const bool diag = (kt == qt);
    float pv[4][4];
    float lad[4] = {0.f, 0.f, 0.f, 0.f};
#pragma unroll
    for (int n = 0; n < 4; ++n)
#pragma unroll
      for (int r = 0; r < 4; ++r) {
        float sv = s4[n][r] * 0.125f;
        if (diag && (n * 16 + c) > (w * 16 + g * 4 + r)) sv = -1e30f;
        float p = __expf(sv);
        pv[n][r] = p;
        lad[r] += p;
      }
#pragma unroll
    for (int off = 1; off < 16; off <<= 1)
#pragma unroll
      for (int r = 0; r < 4; ++r) lad[r] += __shfl_xor(lad[r], off);
#pragma unroll
    for (int r = 0; r < 4; ++r) l_r[r] += lad[r];
#pragma unroll
    for (int n = 0; n < 4; ++n)
#pragma unroll
      for (int r = 0; r < 4; ++r) {
        int q = w * 16 + g * 4 + r;
        int byt = 32 * n + 2 * c;
        int slot = byt >> 4;
        Ps[q * 64 + ((slot ^ (q & 7)) * 8) + ((byt & 15) >> 1)] = f2b(pv[n][r]);
      }
    bf16x8 pf[2];
#pragma unroll
    for (int kq = 0; kq < 2; ++kq) {
      int row = w * 16 + c;
      pf[kq] = *(const bf16x8*)(&Ps[row * 64 + (((kq * 4 + g) ^ (row & 7)) * 8)]);
    }
#pragma unroll
    for (int dn = 0; dn < 4; ++dn) {
#pragma unroll
      for (int kq = 0; kq < 2; ++kq) {
        int row = dn * 16 + c;
        bf16x8 vf = *(const bf16x8*)(&Vs[cur * 4096 + row * 64 +
                                         (((kq * 4 + g) ^ (row & 7)) * 8)]);
        o[dn] = mfma16(pf[kq], vf, o[dn]);
      }
    }
    __syncthreads();
    cur ^= 1;
  }

  float linv[4];
#pragma unroll
  for (int r = 0; r < 4; ++r) linv[r] = c_p / l_r[r];
#pragma unroll
  for (int dn = 0; dn < 4; ++dn) {
#pragma unroll
    for (int r = 0; r < 4; ++r) {
      const size_t row = (size_t)qrow0 + w * 16 + g * 4 + r;
      const int col = h * 64 + dn * 16 + c;
      aexp[row * E + col] = f2b(o[dn][r] * linv[r]);
    }
  }
}

// ---------------- static blend row (wave per (b,q) row) --------------------
__device__ __forceinline__ void dev_blend(int idx, const float* __restrict__ rel,
                                          const float* __restrict__ resp,
                                          const float* __restrict__ ts,
                                          float l1, float l2, float l3,
                                          ushort* __restrict__ stat) {
  const float c_t = (1.f - l3) * (1.f - l1) * l2;
  const float c_r = (1.f - l3) * l1;
  const float c_s = l3;
  const int wave = threadIdx.x >> 6, lane = threadIdx.x & 63;
  const int row = idx * 4 + wave;
  const int qi = row & (L - 1);
  const size_t base = (size_t)row * L;
  float rv[8], sv[8], tv[8];
#pragma unroll
  for (int jj = 0; jj < 8; ++jj) {
    const int k = jj * 64 + lane;
    const float r = rel[base + k];
    const float s = resp[base + k];
    const float tt = ts[base + k];
    const bool fut = (k > qi);
    const float rm = fut ? r : 0.f;
    const float sm = fut ? s : 0.f;
    rv[jj] = (rm == 0.f) ? -1e4f : rm;
    sv[jj] = (sm == 0.f) ? -1e4f : sm;
    tv[jj] = fut ? -INFINITY : __expf(-fabsf(tt));
  }
  float rmax = -INFINITY, smax = -INFINITY, tmax = -INFINITY;
#pragma unroll
  for (int jj = 0; jj < 8; ++jj) {
    rmax = fmaxf(rmax, rv[jj]); smax = fmaxf(smax, sv[jj]); tmax = fmaxf(tmax, tv[jj]);
  }
  for (int off = 1; off < 64; off <<= 1) {
    rmax = fmaxf(rmax, __shfl_xor(rmax, off));
    smax = fmaxf(smax, __shfl_xor(smax, off));
    tmax = fmaxf(tmax, __shfl_xor(tmax, off));
  }
  float rsum = 0.f, ssum = 0.f, tsum = 0.f;
#pragma unroll
  for (int jj = 0; jj < 8; ++jj) {
    rsum += __expf(rv[jj] - rmax); ssum += __expf(sv[jj] - smax); tsum += __expf(tv[jj] - tmax);
  }
  for (int off = 1; off < 64; off <<= 1) {
    rsum += __shfl_xor(rsum, off);
    ssum += __shfl_xor(ssum, off);
    tsum += __shfl_xor(tsum, off);
  }
  const float rinv = c_r / rsum, sinv = c_s / ssum, tinv = c_t / tsum;
#pragma unroll
  for (int jj = 0; jj < 8; ++jj) {
    stat[base + jj * 64 + lane] =
        f2b(__expf(rv[jj] - rmax) * rinv + __expf(sv[jj] - smax) * sinv +
            __expf(tv[jj] - tmax) * tinv);
  }
}

// -------- 32x32 transpose+convert tile body --------------------------------
__device__ __forceinline__ void tcvt_body(const float* __restrict__ src,
                                          ushort* __restrict__ dst, int Kd, int Nd,
                                          int kb, int nb, int t, ushort (*T)[33]) {
  const int r = t >> 3, c4 = (t & 7) * 4;
  float4 v = *(const float4*)(src + (size_t)(kb + r) * Nd + nb + c4);
  T[r][c4 + 0] = f2b(v.x); T[r][c4 + 1] = f2b(v.y);
  T[r][c4 + 2] = f2b(v.z); T[r][c4 + 3] = f2b(v.w);
  __syncthreads();
  ushort4 ov = {T[c4 + 0][r], T[c4 + 1][r], T[c4 + 2][r], T[c4 + 3][r]};
  *(ushort4*)(&dst[(size_t)(nb + r) * Kd + kb + c4]) = ov;
}

// ======== launch 1: Win/Wq0/Wq1 transposes + out init (no big converts) ====
__global__ __launch_bounds__(256) void k_prep(
    const float* __restrict__ Win, const float* __restrict__ Wqkv,
    const float* __restrict__ bf2, ushort* __restrict__ Wint,
    ushort* __restrict__ Wqkvt, float* __restrict__ outv) {
  __shared__ ushort T[32][33];
  const int bi = blockIdx.x;
  const int t = threadIdx.x;
  const long long EE = (long long)E * E;
  if (bi < 1024) {  // Win transpose (2048 x 512)
    tcvt_body(Win, Wint, 2048, 512, (bi >> 4) * 32, (bi & 15) * 32, t, T);
    return;
  }
  if (bi < 1536) {  // Wq0 (z=0) and Wq1 (z=3) transposes
    const int idx = bi - 1024;
    const int z = (idx >= 256) ? 3 : 0;
    const int r = idx & 255;
    tcvt_body(Wqkv + z * EE, Wqkvt + z * EE, 512, 512, (r >> 4) * 32,
              (r & 15) * 32, t, T);
    return;
  }
  {  // init out[m] = bf2[0]  (4 blocks x 256 threads x float4)
    const int i = (bi - 1536) * 256 + t;
    const float b2 = bf2[0];
    float4 v = {b2, b2, b2, b2};
    ((float4*)outv)[i] = v;
  }
}

// ======== launch 2: x-GEMM(f32 A) ∥ q0/q1(f32 A) ∥ k/v+Wf1 transp ∥ blend ==
// XCD swizzle: m-index fastest so blocks sharing an A-panel share bid%8.
__global__ __launch_bounds__(256) void k_xgemm_blend(
    const float* __restrict__ x4e, const float* __restrict__ query,
    const ushort* __restrict__ Wint, const ushort* __restrict__ Wqkvt,
    const float* __restrict__ b_in, const float* __restrict__ bqkv,
    ushort* __restrict__ x_bf, ushort* __restrict__ q_bf,
    ushort* __restrict__ q1_bf, const float* __restrict__ Wqkv,
    const float* __restrict__ Wf1, ushort* __restrict__ Wqkvt_out,
    ushort* __restrict__ Wf1t, const float* __restrict__ rel,
    const float* __restrict__ resp, const float* __restrict__ ts,
    const float* __restrict__ l1p, const float* __restrict__ l2p,
    const float* __restrict__ l3p, ushort* __restrict__ stat) {
  extern __shared__ ushort lds[];
  const int bx = blockIdx.x;
  const long long EE = (long long)E * E;
  if (bx < 256) {  // x = relu(x4e @ Win + b_in), f32-direct A
    dev_gemm<128, 1, 1, 1, 1, 0>(lds, bx >> 5, bx & 31, (const ushort*)x4e,
                                 nullptr, nullptr, nullptr, nullptr, Wint, b_in,
                                 x_bf, nullptr, nullptr, nullptr, nullptr,
                                 2048, 512);
  } else if (bx < 512) {  // q0 = query @ Wq0 + bq0, f32-direct A
    const int r = bx - 256;
    dev_gemm<128, 1, 1, 0, 1, 0>(lds, r >> 5, r & 31, (const ushort*)query,
                                 nullptr, nullptr, nullptr, nullptr, Wqkvt,
                                 bqkv, q_bf, nullptr, nullptr, nullptr, nullptr,
                                 512, 512);
  } else if (bx < 768) {  // q1 = query @ Wq1 + bq1, f32-direct A
    const int r = bx - 512;
    dev_gemm<128, 1, 1, 0, 1, 0>(lds, r >> 5, r & 31, (const ushort*)query,
                                 nullptr, nullptr, nullptr, nullptr,
                                 Wqkvt + 3 * EE, bqkv + 3 * E, q1_bf, nullptr,
                                 nullptr, nullptr, nullptr, 512, 512);
  } else if (bx < 1792) {  // Wqkv z in {1,2,4,5} transposes
    const int idx = bx - 768;
    const int zmap[4] = {1, 2, 4, 5};
    const int z = zmap[idx >> 8];
    const int r = idx & 255;
    tcvt_body(Wqkv + z * EE, Wqkvt_out + z * EE, 512, 512, (r >> 4) * 32,
              (r & 15) * 32, threadIdx.x, (ushort(*)[33])lds);
  } else if (bx < 2304) {  // Wf1 transpose (1024 x 512)
    const int q = bx - 1792;
    tcvt_body(Wf1, Wf1t, 1024, 512, (q >> 4) * 32, (q & 15) * 32,
              threadIdx.x, (ushort(*)[33])lds);
  } else {
    dev_blend(bx - 2304, rel, resp, ts, l1p[0], l2p[0], l3p[0], stat);
  }
}

// ======== launch 3: layer-0 k,v from x_bf (MODE 5), XCD-swizzled ===========
__global__ __launch_bounds__(256) void k_kv0(
    const ushort* __restrict__ x_bf, const ushort* __restrict__ Wt,
    const float* __restrict__ bias, ushort* __restrict__ k_bf,
    ushort* __restrict__ vt) {
  extern __shared__ ushort lds[];
  const int bx = blockIdx.x;  // 512 blocks: m = bx&31 (XCD key), n = bx>>5
  dev_gemm<128, 5, 1, 0, 0, 0>(lds, bx >> 5, bx & 31, nullptr, x_bf,
                               nullptr, nullptr, nullptr, Wt, bias, nullptr,
                               k_bf, vt, nullptr, nullptr, 512, 1024);
}

// ======== launch 4/6: attention (512) ∥ stat-GEMM (256), XCD-swizzled ======
__global__ __launch_bounds__(256) void k_attn_stat(
    const ushort* __restrict__ Qg, const ushort* __restrict__ Kg,
    const ushort* __restrict__ Vt, const ushort* __restrict__ stat,
    const float* __restrict__ l1p, const float* __restrict__ l2p,
    const float* __restrict__ l3p, ushort* __restrict__ aexp,
    ushort* __restrict__ ostat) {
  extern __shared__ ushort lds[];
  const int bx = blockIdx.x;
  if (bx < 512) {
    // hb fastest -> all qt-blocks of one (b,h) on one XCD; qt descending.
    const int hb = bx & 63;
    const int qt = 7 - (bx >> 6);
    const int h = hb & 7, b = hb >> 3;
    const float l1 = l1p[0], l2 = l2p[0], l3 = l3p[0];
    const float c_p = (1.f - l3) * (1.f - l1) * (1.f - l2);
    dev_attn(lds, qt, h, b, Qg, Kg, Vt, c_p, aexp);
  } else {
    // idx = n*32 + (bz*4 + m): bid%8 fixed per (bz,m) A-panel.
    const int idx = bx - 512;
    const int n = idx >> 5;
    const int rem = idx & 31;
    const int bz = rem >> 2, m = rem & 3;
    const long long LLs = (long long)L * L, ELs = (long long)E * L;
    dev_gemm<128, 1, 0, 0, 0, 0>(lds, n, m, stat + bz * LLs, nullptr,
                                 nullptr, nullptr, nullptr, Vt + bz * ELs,
                                 nullptr, ostat + bz * ELs, nullptr, nullptr,
                                 nullptr, nullptr, 512, 512);
  }
}

// ======== launch 5: layer-1 k,v with A = aexp0+ostat0 (MODE 5) =============
__global__ __launch_bounds__(256) void k_kv1(
    const ushort* __restrict__ aexp0, const ushort* __restrict__ ostat0,
    const ushort* __restrict__ Wt, const float* __restrict__ bias,
    ushort* __restrict__ k_bf, ushort* __restrict__ vt) {
  extern __shared__ ushort lds[];
  const int bx = blockIdx.x;  // 512 blocks: m = bx&31, n = bx>>5
  dev_gemm<128, 5, 1, 0, 2, 0>(lds, bx >> 5, bx & 31, aexp0, ostat0,
                               nullptr, nullptr, nullptr, Wt, bias, nullptr,
                               k_bf, vt, nullptr, nullptr, 512, 1024);
}

// ======== launch 7: f1 + fused final dot (atomic); Aq = query f32 ==========
__global__ __launch_bounds__(256) void k_f1(
    const ushort* __restrict__ aexp0, const ushort* __restrict__ ostat0,
    const ushort* __restrict__ aexp1, const ushort* __restrict__ ostat1,
    const float* __restrict__ query, const ushort* __restrict__ Wf1t,
    const float* __restrict__ bf1, const float* __restrict__ Wf2,
    float* __restrict__ outv) {
  extern __shared__ ushort lds[];
  const int bx = blockIdx.x;  // 256 blocks: m = bx&31, n = bx>>5
  dev_gemm<128, 4, 1, 1, 5, 1>(lds, bx >> 5, bx & 31, aexp0, ostat0,
                               aexp1, ostat1, (const ushort*)query, Wf1t, bf1,
                               nullptr, nullptr, nullptr, Wf2, outv, 1024, 512);
}

extern "C" void kernel_launch(void* const* d_in, const int* in_sizes, int n_in,
                              void* d_out, int out_size, void* d_ws, size_t ws_size,
                              hipStream_t stream) {
  (void)in_sizes; (void)n_in; (void)out_size; (void)ws_size;
  const float* inputs_4e = (const float*)d_in[0];
  const float* query = (const float*)d_in[1];
  const float* rel = (const float*)d_in[2];
  const float* resp = (const float*)d_in[3];
  const float* tsp = (const float*)d_in[4];
  const float* l1p = (const float*)d_in[5];
  const float* l2p = (const float*)d_in[6];
  const float* l3p = (const float*)d_in[7];
  const float* Win = (const float*)d_in[8];
  const float* b_in = (const float*)d_in[9];
  const float* Wqkv = (const float*)d_in[10];
  const float* bqkv = (const float*)d_in[11];
  const float* Wf1 = (const float*)d_in[12];
  const float* bf1 = (const float*)d_in[13];
  const float* Wf2 = (const float*)d_in[14];
  const float* bf2 = (const float*)d_in[15];

  char* ws = (char*)d_ws;
  const size_t MB = 1ull << 20;
  ushort* aexp0   = (ushort*)(ws + 0 * MB);   // 4MB (written launch 4)
  ushort* ostat0  = (ushort*)(ws + 4 * MB);   // 4MB (written launch 4)
  ushort* aexp1   = (ushort*)(ws + 8 * MB);   // 4MB (written launch 6)
  ushort* ostat1  = (ushort*)(ws + 12 * MB);  // 4MB (written launch 6)
  ushort* stat_bf = (ushort*)(ws + 20 * MB);  // 4MB
  ushort* x_bf    = (ushort*)(ws + 24 * MB);  // 4MB
  ushort* q_bf    = (ushort*)(ws + 28 * MB);  // 4MB
  ushort* k_bf    = (ushort*)(ws + 32 * MB);  // 4MB
  ushort* vt      = (ushort*)(ws + 36 * MB);  // 4MB (B,E,L)
  ushort* q1_bf   = (ushort*)(ws + 40 * MB);  // 4MB
  ushort* Wint    = (ushort*)(ws + 48 * MB);  // 2MB
  ushort* Wqkvt   = (ushort*)(ws + 50 * MB);  // 3MB
  ushort* Wf1t    = (ushort*)(ws + 53 * MB);  // 1MB

  const long long EE = (long long)E * E;
  const int LDS_G128 = (2 * 128 * 64 + 2 * 64 * 64) * 2;  // 49152
  const int LDS_AS = 49152;

  // 1) Win/Wq0/Wq1 transposes + out init (out[m] = bf2)
  k_prep<<<1024 + 512 + 4, 256, 0, stream>>>(Win, Wqkv, bf2, Wint, Wqkvt,
                                             (float*)d_out);
  // 2) x-GEMM (f32 A) ∥ q0 ∥ q1 ∥ k/v+Wf1 transposes ∥ static blend
  k_xgemm_blend<<<256 + 512 + 1024 + 512 + 1024, 256, LDS_G128, stream>>>(
      inputs_4e, query, Wint, Wqkvt, b_in, bqkv, x_bf, q_bf, q1_bf,
      Wqkv, Wf1, Wqkvt, Wf1t, rel, resp, tsp, l1p, l2p, l3p, stat_bf);
  // 3) layer-0 k,v
  k_kv0<<<512, 256, LDS_G128, stream>>>(x_bf, Wqkvt + 1 * EE,
                                        bqkv + 1 * E, k_bf, vt);
  // 4) attn0 ∥ stat0
  k_attn_stat<<<768, 256, LDS_AS, stream>>>(q_bf, k_bf, vt, stat_bf,
                                            l1p, l2p, l3p, aexp0, ostat0);
  // 5) layer-1 k,v (A = aexp0 + ostat0)
  k_kv1<<<512, 256, LDS_G128, stream>>>(aexp0, ostat0, Wqkvt + 4 * EE,
                                        bqkv + 4 * E, k_bf, vt);
  // 6) attn1 ∥ stat1
  k_attn_stat<<<768, 256, LDS_AS, stream>>>(q1_bf, k_bf, vt, stat_bf,
                                            l1p, l2p, l3p, aexp1, ostat1);
  // 7) f1 + fused final dot: out[m] = bf2 + sum_n relu(...)*Wf2[n]
  k_f1<<<256, 256, LDS_G128, stream>>>(aexp0, ostat0, aexp1, ostat1,
                                       query, Wf1t, bf1, Wf2,
                                       (float*)d_out);
}

// Round 15
// 119.379 us; speedup vs baseline: 1.3144x; 1.3144x over previous
//
#include <hip/hip_runtime.h>
#include <math.h>

namespace {
constexpr int B = 8, L = 512, E = 512, H = 8;
constexpr int M = B * L;  // 4096
}

typedef float f32x4 __attribute__((ext_vector_type(4)));
typedef short bf16x8 __attribute__((ext_vector_type(8)));

__device__ inline ushort f2b(float f) {
  unsigned u = __float_as_uint(f);
  u += 0x7FFF + ((u >> 16) & 1);
  return (ushort)(u >> 16);
}
__device__ inline float b2f(ushort h) { return __uint_as_float(((unsigned)h) << 16); }

__device__ inline f32x4 mfma16(bf16x8 a, bf16x8 b, f32x4 c) {
  return __builtin_amdgcn_mfma_f32_16x16x32_bf16(a, b, c, 0, 0, 0);
}

// async global->LDS 16B per lane (LDS dest = wave-uniform base + lane*16)
__device__ __forceinline__ void gl2lds16(const ushort* g, ushort* l) {
  __builtin_amdgcn_global_load_lds(
      (const __attribute__((address_space(1))) void*)g,
      (__attribute__((address_space(3))) void*)l, 16, 0, 0);
}

// Stage NROWS x 64 bf16 tile into linear LDS [row][64] with inverse-XOR-swizzled
// SOURCE: LDS slot s of row r holds global chunk s^(r&7).
template <int NROWS>
__device__ __forceinline__ void stage64(const ushort* __restrict__ g, int ldg,
                                        ushort* lds, int tid) {
  const int w = tid >> 6, l = tid & 63;
  constexpr int RPW = NROWS / 4;
  constexpr int NI = RPW / 8;
#pragma unroll
  for (int it = 0; it < NI; ++it) {
    const int rbase = w * RPW + it * 8;
    const int row = rbase + (l >> 3);
    const int chunk = (l & 7) ^ (row & 7);
    gl2lds16(g + (size_t)row * ldg + chunk * 8, lds + rbase * 64);
  }
}

// reg-staged combine of bf16 buffers (row stride 512) into swizzled LDS tile.
// NBUF=2: b0+b1.  NBUF=4: (b0+b1)+relu(b2+b3).
template <int BM, int NBUF>
__device__ __forceinline__ void stage_comb(const ushort* b0, const ushort* b1,
                                           const ushort* b2, const ushort* b3,
                                           ushort* lds, int tid) {
#pragma unroll
  for (int it = 0; it < BM / 32; ++it) {
    const int row = (tid >> 3) + it * 32;
    const int slot = tid & 7;
    const size_t off = (size_t)row * 512 + slot * 8;
    union Uu { uint4 u; ushort s[8]; } va, vb, vc, vd, vo;
    va.u = *(const uint4*)(b0 + off);
    vb.u = *(const uint4*)(b1 + off);
    if (NBUF == 4) {
      vc.u = *(const uint4*)(b2 + off);
      vd.u = *(const uint4*)(b3 + off);
    }
#pragma unroll
    for (int e = 0; e < 8; ++e) {
      float f = b2f(va.s[e]) + b2f(vb.s[e]);
      if (NBUF == 4) f += fmaxf(b2f(vc.s[e]) + b2f(vd.s[e]), 0.f);
      vo.s[e] = f2b(f);
    }
    *(uint4*)(&lds[row * 64 + ((slot ^ (row & 7)) * 8)]) = vo.u;
  }
}

// ------------- 2-phase double-buffered MFMA GEMM core -----------------------
// A:(rows x K) bf16 rm, Wt:(N x K) bf16 rm. BK=64, one barrier per K-tile.
// MODE 1: C0 (rows x N).  MODE 5: 2 secs k(C1)|v(C2 transposed (B,E,L)).
// MODE 4: split-A f1 (K-tiles 0..7 comb4, 8..15 from Aq).
// STAGEA 0: gl2lds. 2: comb2(A,A2). 4: t<8 comb4(A,A2,A3,A4), t>=8 Aq.
// FUSE 1: epilogue = atomic dot with w2 into outv (instead of C store).
template <int BM, int MODE, int HAS_BIAS, int ACT, int STAGEA, int FUSE>
__device__ __forceinline__ void dev_gemm(
    ushort* lds, int bxx, int by, const ushort* A, const ushort* A2,
    const ushort* A3, const ushort* A4, const ushort* Aq,
    const ushort* Wt, const float* bias, ushort* C0, ushort* C1, ushort* C2,
    const float* w2, float* outv, int K, int N) {
  ushort* Als = lds;
  ushort* Bls = lds + 2 * BM * 64;
  const int tid = threadIdx.x;
  const int l = tid & 63, wv = tid >> 6;
  const int wr = wv >> 1, wc = wv & 1;
  const int g = l >> 4, c = l & 15;
  constexpr int WM = BM / 2;
  constexpr int MFR = WM / 16;
  const int bm = by * BM;
  const int bn64 = bxx * 64;
  const int sec = (MODE == 5) ? (bn64 >> 9) : 0;
  const bool vsec = (MODE == 5 && sec == 1);

  const ushort* Ause = (MODE == 5) ? A2 : A;
  const int ldA = K;
  const ushort* Bp = Wt + (size_t)bn64 * K;

  f32x4 acc[MFR][2];
#pragma unroll
  for (int mi = 0; mi < MFR; ++mi)
#pragma unroll
    for (int ni = 0; ni < 2; ++ni) acc[mi][ni] = f32x4{0.f, 0.f, 0.f, 0.f};

  auto stageA = [&](int t, int buf) {
    ushort* dst = Als + buf * BM * 64;
    if (STAGEA == 0) {
      stage64<BM>(Ause + (size_t)bm * ldA + t * 64, ldA, dst, tid);
    } else if (STAGEA == 2) {
      stage_comb<BM, 2>(A + (size_t)bm * 512 + t * 64,
                        A2 + (size_t)bm * 512 + t * 64, nullptr, nullptr, dst, tid);
    } else {
      if (t < 8)
        stage_comb<BM, 4>(A + (size_t)bm * 512 + t * 64,
                          A2 + (size_t)bm * 512 + t * 64,
                          A3 + (size_t)bm * 512 + t * 64,
                          A4 + (size_t)bm * 512 + t * 64, dst, tid);
      else
        stage64<BM>(Aq + (size_t)bm * 512 + (t - 8) * 64, 512, dst, tid);
    }
  };

  stageA(0, 0);
  stage64<64>(Bp, K, Bls, tid);
  __syncthreads();

  const int NT = K >> 6;
  int cur = 0;
  for (int t = 0; t < NT; ++t) {
    if (t + 1 < NT) {
      stageA(t + 1, cur ^ 1);
      stage64<64>(Bp + (t + 1) * 64, K, Bls + (cur ^ 1) * 64 * 64, tid);
    }
#pragma unroll
    for (int ks = 0; ks < 2; ++ks) {
      bf16x8 af[MFR], bf_[2];
#pragma unroll
      for (int mi = 0; mi < MFR; ++mi) {
        const int row = wr * WM + mi * 16 + c;
        af[mi] = *(const bf16x8*)(&Als[cur * BM * 64 + row * 64 +
                                       (((ks * 4 + g) ^ (row & 7)) * 8)]);
      }
#pragma unroll
      for (int ni = 0; ni < 2; ++ni) {
        const int row = wc * 32 + ni * 16 + c;
        bf_[ni] = *(const bf16x8*)(&Bls[cur * 64 * 64 + row * 64 +
                                        (((ks * 4 + g) ^ (row & 7)) * 8)]);
      }
      if (vsec) {
#pragma unroll
        for (int mi = 0; mi < MFR; ++mi)
#pragma unroll
          for (int ni = 0; ni < 2; ++ni)
            acc[mi][ni] = mfma16(bf_[ni], af[mi], acc[mi][ni]);
      } else {
#pragma unroll
        for (int mi = 0; mi < MFR; ++mi)
#pragma unroll
          for (int ni = 0; ni < 2; ++ni)
            acc[mi][ni] = mfma16(af[mi], bf_[ni], acc[mi][ni]);
      }
    }
    __syncthreads();
    cur ^= 1;
  }

  if (FUSE) {
    // out[m] += sum_n relu(acc + bf1[n]) * w2[n]; out pre-init'd to bf2.
    float w2v[2];
#pragma unroll
    for (int ni = 0; ni < 2; ++ni) w2v[ni] = w2[bn64 + wc * 32 + ni * 16 + c];
#pragma unroll
    for (int mi = 0; mi < MFR; ++mi) {
#pragma unroll
      for (int r = 0; r < 4; ++r) {
        float p = 0.f;
#pragma unroll
        for (int ni = 0; ni < 2; ++ni) {
          const int n = bn64 + wc * 32 + ni * 16 + c;
          float v = acc[mi][ni][r] + bias[n];
          v = fmaxf(v, 0.f);
          p += v * w2v[ni];
        }
        p += __shfl_xor(p, 1);
        p += __shfl_xor(p, 2);
        p += __shfl_xor(p, 4);
        p += __shfl_xor(p, 8);
        if (c == 0) atomicAdd(&outv[bm + wr * WM + mi * 16 + g * 4 + r], p);
      }
    }
  } else if (vsec) {
    // swapped acc: D rows = E-dim, cols = tokens -> vt (B,E,L)
    const int e0 = bn64 - 512;
#pragma unroll
    for (int ni = 0; ni < 2; ++ni) {
#pragma unroll
      for (int r = 0; r < 4; ++r) {
        const int e = e0 + wc * 32 + ni * 16 + g * 4 + r;
        const float bv = HAS_BIAS ? bias[512 + e] : 0.f;
#pragma unroll
        for (int mi = 0; mi < MFR; ++mi) {
          const int m = bm + wr * WM + mi * 16 + c;
          const int bb = m >> 9, lt = m & 511;
          C2[((size_t)bb * 512 + e) * 512 + lt] = f2b(acc[mi][ni][r] + bv);
        }
      }
    }
  } else {
    ushort* dst = (MODE == 5) ? C1 : C0;
    const int nsub = (MODE == 5) ? sec * 512 : 0;
    const int ldc = (MODE == 5) ? 512 : N;
#pragma unroll
    for (int ni = 0; ni < 2; ++ni) {
      const int n = bn64 + wc * 32 + ni * 16 + c;
      const float bv = HAS_BIAS ? bias[n] : 0.f;
#pragma unroll
      for (int mi = 0; mi < MFR; ++mi) {
#pragma unroll
        for (int r = 0; r < 4; ++r) {
          const int m = bm + wr * WM + mi * 16 + g * 4 + r;
          float v = acc[mi][ni][r] + bv;
          if (ACT) v = fmaxf(v, 0.f);
          dst[(size_t)m * ldc + (n - nsub)] = f2b(v);
        }
      }
    }
  }
}

// ---------------- attention core: aexp = (c_p/l) * sum exp(QK^T/8) V --------
__device__ __forceinline__ void dev_attn(ushort* lds, int qt, int h, int b,
                                         const ushort* __restrict__ Qg,
                                         const ushort* __restrict__ Kg,
                                         const ushort* __restrict__ Vt,
                                         float c_p, ushort* __restrict__ aexp) {
  ushort* Qs = lds;           // 4096
  ushort* Ps = lds + 4096;    // 4096
  ushort* Ks = lds + 8192;    // 2 x 4096
  ushort* Vs = lds + 16384;   // 2 x 4096
  const int tid = threadIdx.x, l = tid & 63, w = tid >> 6;
  const int g = l >> 4, c = l & 15;
  const int qrow0 = b * L + qt * 64;
  const ushort* Kbase = Kg + (size_t)(b * L) * E + h * 64;
  const ushort* Vbase = Vt + (size_t)(b * E + h * 64) * L;

  stage64<64>(Qg + (size_t)qrow0 * E + h * 64, E, Qs, tid);
  stage64<64>(Kbase, E, Ks, tid);
  stage64<64>(Vbase, L, Vs, tid);
  __syncthreads();

  f32x4 o[4];
#pragma unroll
  for (int dn = 0; dn < 4; ++dn) o[dn] = f32x4{0.f, 0.f, 0.f, 0.f};
  float l_r[4] = {0.f, 0.f, 0.f, 0.f};

  int cur = 0;
  for (int kt = 0; kt <= qt; ++kt) {
    if (kt < qt) {
      stage64<64>(Kbase + (size_t)(kt + 1) * 64 * E, E, Ks + (cur ^ 1) * 4096, tid);
      stage64<64>(Vbase + (kt + 1) * 64, L, Vs + (cur ^ 1) * 4096, tid);
    }
    bf16x8 qf[2];
#pragma unroll
    for (int kq = 0; kq < 2; ++kq) {
      int row = w * 16 + c;
      qf[kq] = *(const bf16x8*)(&Qs[row * 64 + (((kq * 4 + g) ^ (row & 7)) * 8)]);
    }
    f32x4 s4[4];
#pragma unroll
    for (int n = 0; n < 4; ++n) s4[n] = f32x4{0.f, 0.f, 0.f, 0.f};
#pragma unroll
    for (int n = 0; n < 4; ++n) {
#pragma unroll
      for (int kq = 0; kq < 2; ++kq) {
        int row = n * 16 + c;
        bf16x8 kf = *(const bf16x8*)(&Ks[cur * 4096 + row * 64 +
                                         (((kq * 4 + g) ^ (row & 7)) * 8)]);
        s4[n] = mfma16(qf[kq], kf, s4[n]);
      }
    }
    // P = exp(S/8), no max subtraction (|S/8| bounded; masked -> 0)
    const bool diag = (kt == qt);
    float pv[4][4];
    float lad[4] = {0.f, 0.f, 0.f, 0.f};
#pragma unroll
    for (int n = 0; n < 4; ++n)
#pragma unroll
      for (int r = 0; r < 4; ++r) {
        float sv = s4[n][r] * 0.125f;
        if (diag && (n * 16 + c) > (w * 16 + g * 4 + r)) sv = -1e30f;
        float p = __expf(sv);
        pv[n][r] = p;
        lad[r] += p;
      }
#pragma unroll
    for (int off = 1; off < 16; off <<= 1)
#pragma unroll
      for (int r = 0; r < 4; ++r) lad[r] += __shfl_xor(lad[r], off);
#pragma unroll
    for (int r = 0; r < 4; ++r) l_r[r] += lad[r];
#pragma unroll
    for (int n = 0; n < 4; ++n)
#pragma unroll
      for (int r = 0; r < 4; ++r) {
        int q = w * 16 + g * 4 + r;
        int byt = 32 * n + 2 * c;
        int slot = byt >> 4;
        Ps[q * 64 + ((slot ^ (q & 7)) * 8) + ((byt & 15) >> 1)] = f2b(pv[n][r]);
      }
    bf16x8 pf[2];
#pragma unroll
    for (int kq = 0; kq < 2; ++kq) {
      int row = w * 16 + c;
      pf[kq] = *(const bf16x8*)(&Ps[row * 64 + (((kq * 4 + g) ^ (row & 7)) * 8)]);
    }
#pragma unroll
    for (int dn = 0; dn < 4; ++dn) {
#pragma unroll
      for (int kq = 0; kq < 2; ++kq) {
        int row = dn * 16 + c;
        bf16x8 vf = *(const bf16x8*)(&Vs[cur * 4096 + row * 64 +
                                         (((kq * 4 + g) ^ (row & 7)) * 8)]);
        o[dn] = mfma16(pf[kq], vf, o[dn]);
      }
    }
    __syncthreads();
    cur ^= 1;
  }

  float linv[4];
#pragma unroll
  for (int r = 0; r < 4; ++r) linv[r] = c_p / l_r[r];
#pragma unroll
  for (int dn = 0; dn < 4; ++dn) {
#pragma unroll
    for (int r = 0; r < 4; ++r) {
      const size_t row = (size_t)qrow0 + w * 16 + g * 4 + r;
      const int col = h * 64 + dn * 16 + c;
      aexp[row * E + col] = f2b(o[dn][r] * linv[r]);
    }
  }
}

// ---------------- static blend row (wave per (b,q) row) --------------------
__device__ __forceinline__ void dev_blend(int idx, const float* __restrict__ rel,
                                          const float* __restrict__ resp,
                                          const float* __restrict__ ts,
                                          float l1, float l2, float l3,
                                          ushort* __restrict__ stat) {
  const float c_t = (1.f - l3) * (1.f - l1) * l2;
  const float c_r = (1.f - l3) * l1;
  const float c_s = l3;
  const int wave = threadIdx.x >> 6, lane = threadIdx.x & 63;
  const int row = idx * 4 + wave;
  const int qi = row & (L - 1);
  const size_t base = (size_t)row * L;
  float rv[8], sv[8], tv[8];
#pragma unroll
  for (int jj = 0; jj < 8; ++jj) {
    const int k = jj * 64 + lane;
    const float r = rel[base + k];
    const float s = resp[base + k];
    const float tt = ts[base + k];
    const bool fut = (k > qi);
    const float rm = fut ? r : 0.f;
    const float sm = fut ? s : 0.f;
    rv[jj] = (rm == 0.f) ? -1e4f : rm;
    sv[jj] = (sm == 0.f) ? -1e4f : sm;
    tv[jj] = fut ? -INFINITY : __expf(-fabsf(tt));
  }
  float rmax = -INFINITY, smax = -INFINITY, tmax = -INFINITY;
#pragma unroll
  for (int jj = 0; jj < 8; ++jj) {
    rmax = fmaxf(rmax, rv[jj]); smax = fmaxf(smax, sv[jj]); tmax = fmaxf(tmax, tv[jj]);
  }
  for (int off = 1; off < 64; off <<= 1) {
    rmax = fmaxf(rmax, __shfl_xor(rmax, off));
    smax = fmaxf(smax, __shfl_xor(smax, off));
    tmax = fmaxf(tmax, __shfl_xor(tmax, off));
  }
  float rsum = 0.f, ssum = 0.f, tsum = 0.f;
#pragma unroll
  for (int jj = 0; jj < 8; ++jj) {
    rsum += __expf(rv[jj] - rmax); ssum += __expf(sv[jj] - smax); tsum += __expf(tv[jj] - tmax);
  }
  for (int off = 1; off < 64; off <<= 1) {
    rsum += __shfl_xor(rsum, off);
    ssum += __shfl_xor(ssum, off);
    tsum += __shfl_xor(tsum, off);
  }
  const float rinv = c_r / rsum, sinv = c_s / ssum, tinv = c_t / tsum;
#pragma unroll
  for (int jj = 0; jj < 8; ++jj) {
    stat[base + jj * 64 + lane] =
        f2b(__expf(rv[jj] - rmax) * rinv + __expf(sv[jj] - smax) * sinv +
            __expf(tv[jj] - tmax) * tinv);
  }
}

// -------- 32x32 transpose+convert tile body --------------------------------
__device__ __forceinline__ void tcvt_body(const float* __restrict__ src,
                                          ushort* __restrict__ dst, int Kd, int Nd,
                                          int kb, int nb, int t, ushort (*T)[33]) {
  const int r = t >> 3, c4 = (t & 7) * 4;
  float4 v = *(const float4*)(src + (size_t)(kb + r) * Nd + nb + c4);
  T[r][c4 + 0] = f2b(v.x); T[r][c4 + 1] = f2b(v.y);
  T[r][c4 + 2] = f2b(v.z); T[r][c4 + 3] = f2b(v.w);
  __syncthreads();
  ushort4 ov = {T[c4 + 0][r], T[c4 + 1][r], T[c4 + 2][r], T[c4 + 3][r]};
  *(ushort4*)(&dst[(size_t)(nb + r) * Kd + kb + c4]) = ov;
}

// ======== launch 1: converts (4x strided) + Win/Wq0/Wq1 transp + out init ==
__global__ __launch_bounds__(256) void k_prep(
    const float* __restrict__ x4e, const float* __restrict__ query,
    const float* __restrict__ Win, const float* __restrict__ Wqkv,
    const float* __restrict__ bf2, ushort* __restrict__ x4e_bf,
    ushort* __restrict__ qbf, ushort* __restrict__ Wint,
    ushort* __restrict__ Wqkvt, float* __restrict__ outv) {
  __shared__ ushort T[32][33];
  const int bi = blockIdx.x;
  const int t = threadIdx.x;
  const long long EE = (long long)E * E;
  if (bi < 2560) {  // converts: 2560 blocks x 4 x 256 float4
    const int N1 = M * 2048 / 4;  // 2097152
#pragma unroll
    for (int it = 0; it < 4; ++it) {
      int i = bi * 1024 + it * 256 + t;
      if (i < N1) {
        float4 v = ((const float4*)x4e)[i];
        ushort4 o = {f2b(v.x), f2b(v.y), f2b(v.z), f2b(v.w)};
        ((ushort4*)x4e_bf)[i] = o;
      } else {
        int j = i - N1;
        float4 v = ((const float4*)query)[j];
        ushort4 o = {f2b(v.x), f2b(v.y), f2b(v.z), f2b(v.w)};
        ((ushort4*)qbf)[j] = o;
      }
    }
    return;
  }
  if (bi < 3584) {  // Win transpose (2048 x 512)
    const int idx = bi - 2560;
    tcvt_body(Win, Wint, 2048, 512, (idx >> 4) * 32, (idx & 15) * 32, t, T);
    return;
  }
  if (bi < 4096) {  // Wq0 (z=0) and Wq1 (z=3) transposes
    const int idx = bi - 3584;
    const int z = (idx >= 256) ? 3 : 0;
    const int r = idx & 255;
    tcvt_body(Wqkv + z * EE, Wqkvt + z * EE, 512, 512, (r >> 4) * 32,
              (r & 15) * 32, t, T);
    return;
  }
  {  // init out[m] = bf2[0]
    const int i = (bi - 4096) * 256 + t;
    const float b2 = bf2[0];
    float4 v = {b2, b2, b2, b2};
    ((float4*)outv)[i] = v;
  }
}

// ======== launch 2: x-GEMM ∥ q0 ∥ q1 ∥ k/v+Wf1 transposes ∥ blend ==========
// XCD swizzle: m-index is the fastest-varying bit of blockIdx so that blocks
// sharing an A-panel get the same bid%8 -> same XCD L2.
__global__ __launch_bounds__(256) void k_xgemm_blend(
    const ushort* __restrict__ x4e_bf, const ushort* __restrict__ query_bf,
    const ushort* __restrict__ Wint, const ushort* __restrict__ Wqkvt,
    const float* __restrict__ b_in, const float* __restrict__ bqkv,
    ushort* __restrict__ x_bf, ushort* __restrict__ q_bf,
    ushort* __restrict__ q1_bf, const float* __restrict__ Wqkv,
    const float* __restrict__ Wf1, ushort* __restrict__ Wqkvt_out,
    ushort* __restrict__ Wf1t, const float* __restrict__ rel,
    const float* __restrict__ resp, const float* __restrict__ ts,
    const float* __restrict__ l1p, const float* __restrict__ l2p,
    const float* __restrict__ l3p, ushort* __restrict__ stat) {
  extern __shared__ ushort lds[];
  const int bx = blockIdx.x;
  const long long EE = (long long)E * E;
  if (bx < 256) {  // x = relu(x4e @ Win + b_in): m = bx&31 (XCD key), n = bx>>5
    dev_gemm<128, 1, 1, 1, 0, 0>(lds, bx >> 5, bx & 31, x4e_bf, nullptr, nullptr,
                                 nullptr, nullptr, Wint, b_in, x_bf, nullptr,
                                 nullptr, nullptr, nullptr, 2048, 512);
  } else if (bx < 512) {  // q0 = query @ Wq0 + bq0
    const int r = bx - 256;
    dev_gemm<128, 1, 1, 0, 0, 0>(lds, r >> 5, r & 31, query_bf, nullptr, nullptr,
                                 nullptr, nullptr, Wqkvt, bqkv, q_bf, nullptr,
                                 nullptr, nullptr, nullptr, 512, 512);
  } else if (bx < 768) {  // q1 = query @ Wq1 + bq1
    const int r = bx - 512;
    dev_gemm<128, 1, 1, 0, 0, 0>(lds, r >> 5, r & 31, query_bf, nullptr, nullptr,
                                 nullptr, nullptr, Wqkvt + 3 * EE, bqkv + 3 * E,
                                 q1_bf, nullptr, nullptr, nullptr, nullptr, 512, 512);
  } else if (bx < 1792) {  // Wqkv z in {1,2,4,5} transposes
    const int idx = bx - 768;
    const int zmap[4] = {1, 2, 4, 5};
    const int z = zmap[idx >> 8];
    const int r = idx & 255;
    tcvt_body(Wqkv + z * EE, Wqkvt_out + z * EE, 512, 512, (r >> 4) * 32,
              (r & 15) * 32, threadIdx.x, (ushort(*)[33])lds);
  } else if (bx < 2304) {  // Wf1 transpose (1024 x 512)
    const int q = bx - 1792;
    tcvt_body(Wf1, Wf1t, 1024, 512, (q >> 4) * 32, (q & 15) * 32,
              threadIdx.x, (ushort(*)[33])lds);
  } else {
    dev_blend(bx - 2304, rel, resp, ts, l1p[0], l2p[0], l3p[0], stat);
  }
}

// ======== launch 3: layer-0 k,v from x_bf (MODE 5), XCD-swizzled ===========
__global__ __launch_bounds__(256) void k_kv0(
    const ushort* __restrict__ x_bf, const ushort* __restrict__ Wt,
    const float* __restrict__ bias, ushort* __restrict__ k_bf,
    ushort* __restrict__ vt) {
  extern __shared__ ushort lds[];
  const int bx = blockIdx.x;  // 512 blocks: m = bx&31 (XCD key), n = bx>>5
  dev_gemm<128, 5, 1, 0, 0, 0>(lds, bx >> 5, bx & 31, nullptr, x_bf,
                               nullptr, nullptr, nullptr, Wt, bias, nullptr,
                               k_bf, vt, nullptr, nullptr, 512, 1024);
}

// ======== launch 4/6: attention (512) ∥ stat-GEMM (256), XCD-swizzled ======
__global__ __launch_bounds__(256) void k_attn_stat(
    const ushort* __restrict__ Qg, const ushort* __restrict__ Kg,
    const ushort* __restrict__ Vt, const ushort* __restrict__ stat,
    const float* __restrict__ l1p, const float* __restrict__ l2p,
    const float* __restrict__ l3p, ushort* __restrict__ aexp,
    ushort* __restrict__ ostat) {
  extern __shared__ ushort lds[];
  const int bx = blockIdx.x;
  if (bx < 512) {
    // hb fastest -> bid%8 = (h,b)%8: all qt-blocks of one (b,h) on one XCD;
    // qt descending with qt as the slow index keeps heavy-tiles-first.
    const int hb = bx & 63;
    const int qt = 7 - (bx >> 6);
    const int h = hb & 7, b = hb >> 3;
    const float l1 = l1p[0], l2 = l2p[0], l3 = l3p[0];
    const float c_p = (1.f - l3) * (1.f - l1) * (1.f - l2);
    dev_attn(lds, qt, h, b, Qg, Kg, Vt, c_p, aexp);
  } else {
    // idx = n*32 + (bz*4 + m): bid%8 fixed per (bz,m) A-panel.
    const int idx = bx - 512;
    const int n = idx >> 5;
    const int rem = idx & 31;
    const int bz = rem >> 2, m = rem & 3;
    const long long LLs = (long long)L * L, ELs = (long long)E * L;
    dev_gemm<128, 1, 0, 0, 0, 0>(lds, n, m, stat + bz * LLs, nullptr,
                                 nullptr, nullptr, nullptr, Vt + bz * ELs,
                                 nullptr, ostat + bz * ELs, nullptr, nullptr,
                                 nullptr, nullptr, 512, 512);
  }
}

// ======== launch 5: layer-1 k,v with A = aexp0+ostat0 (MODE 5) =============
__global__ __launch_bounds__(256) void k_kv1(
    const ushort* __restrict__ aexp0, const ushort* __restrict__ ostat0,
    const ushort* __restrict__ Wt, const float* __restrict__ bias,
    ushort* __restrict__ k_bf, ushort* __restrict__ vt) {
  extern __shared__ ushort lds[];
  const int bx = blockIdx.x;  // 512 blocks: m = bx&31, n = bx>>5
  dev_gemm<128, 5, 1, 0, 2, 0>(lds, bx >> 5, bx & 31, aexp0, ostat0,
                               nullptr, nullptr, nullptr, Wt, bias, nullptr,
                               k_bf, vt, nullptr, nullptr, 512, 1024);
}

// ======== launch 7: f1 + fused final dot (atomic), XCD-swizzled ============
__global__ __launch_bounds__(256) void k_f1(
    const ushort* __restrict__ aexp0, const ushort* __restrict__ ostat0,
    const ushort* __restrict__ aexp1, const ushort* __restrict__ ostat1,
    const ushort* __restrict__ query_bf, const ushort* __restrict__ Wf1t,
    const float* __restrict__ bf1, const float* __restrict__ Wf2,
    float* __restrict__ outv) {
  extern __shared__ ushort lds[];
  const int bx = blockIdx.x;  // 256 blocks: m = bx&31, n = bx>>5
  dev_gemm<128, 4, 1, 1, 4, 1>(lds, bx >> 5, bx & 31, aexp0, ostat0,
                               aexp1, ostat1, query_bf, Wf1t, bf1, nullptr,
                               nullptr, nullptr, Wf2, outv, 1024, 512);
}

extern "C" void kernel_launch(void* const* d_in, const int* in_sizes, int n_in,
                              void* d_out, int out_size, void* d_ws, size_t ws_size,
                              hipStream_t stream) {
  (void)in_sizes; (void)n_in; (void)out_size; (void)ws_size;
  const float* inputs_4e = (const float*)d_in[0];
  const float* query = (const float*)d_in[1];
  const float* rel = (const float*)d_in[2];
  const float* resp = (const float*)d_in[3];
  const float* tsp = (const float*)d_in[4];
  const float* l1p = (const float*)d_in[5];
  const float* l2p = (const float*)d_in[6];
  const float* l3p = (const float*)d_in[7];
  const float* Win = (const float*)d_in[8];
  const float* b_in = (const float*)d_in[9];
  const float* Wqkv = (const float*)d_in[10];
  const float* bqkv = (const float*)d_in[11];
  const float* Wf1 = (const float*)d_in[12];
  const float* bf1 = (const float*)d_in[13];
  const float* Wf2 = (const float*)d_in[14];
  const float* bf2 = (const float*)d_in[15];

  char* ws = (char*)d_ws;
  const size_t MB = 1ull << 20;
  ushort* x4e_bf  = (ushort*)(ws + 0 * MB);   // 16MB; dead after launch 2
  ushort* aexp0   = (ushort*)(ws + 0 * MB);   // 4MB (written launch 4)
  ushort* ostat0  = (ushort*)(ws + 4 * MB);   // 4MB (written launch 4)
  ushort* aexp1   = (ushort*)(ws + 8 * MB);   // 4MB (written launch 6)
  ushort* ostat1  = (ushort*)(ws + 12 * MB);  // 4MB (written launch 6)
  ushort* query_bf= (ushort*)(ws + 16 * MB);  // 4MB
  ushort* stat_bf = (ushort*)(ws + 20 * MB);  // 4MB
  ushort* x_bf    = (ushort*)(ws + 24 * MB);  // 4MB
  ushort* q_bf    = (ushort*)(ws + 28 * MB);  // 4MB
  ushort* k_bf    = (ushort*)(ws + 32 * MB);  // 4MB
  ushort* vt      = (ushort*)(ws + 36 * MB);  // 4MB (B,E,L)
  ushort* q1_bf   = (ushort*)(ws + 40 * MB);  // 4MB
  ushort* Wint    = (ushort*)(ws + 48 * MB);  // 2MB
  ushort* Wqkvt   = (ushort*)(ws + 50 * MB);  // 3MB
  ushort* Wf1t    = (ushort*)(ws + 53 * MB);  // 1MB

  const long long EE = (long long)E * E;
  const int LDS_G128 = (2 * 128 * 64 + 2 * 64 * 64) * 2;  // 49152
  const int LDS_AS = 49152;

  // 1) converts + Win/Wq0/Wq1 transposes + out init
  k_prep<<<2560 + 1024 + 512 + 4, 256, 0, stream>>>(
      inputs_4e, query, Win, Wqkv, bf2, x4e_bf, query_bf, Wint, Wqkvt,
      (float*)d_out);
  // 2) x-GEMM ∥ q0 ∥ q1 ∥ k/v+Wf1 transposes ∥ static blend
  k_xgemm_blend<<<256 + 512 + 1024 + 512 + 1024, 256, LDS_G128, stream>>>(
      x4e_bf, query_bf, Wint, Wqkvt, b_in, bqkv, x_bf, q_bf, q1_bf,
      Wqkv, Wf1, Wqkvt, Wf1t, rel, resp, tsp, l1p, l2p, l3p, stat_bf);
  // 3) layer-0 k,v
  k_kv0<<<512, 256, LDS_G128, stream>>>(x_bf, Wqkvt + 1 * EE,
                                        bqkv + 1 * E, k_bf, vt);
  // 4) attn0 ∥ stat0
  k_attn_stat<<<768, 256, LDS_AS, stream>>>(q_bf, k_bf, vt, stat_bf,
                                            l1p, l2p, l3p, aexp0, ostat0);
  // 5) layer-1 k,v (A = aexp0 + ostat0)
  k_kv1<<<512, 256, LDS_G128, stream>>>(aexp0, ostat0, Wqkvt + 4 * EE,
                                        bqkv + 4 * E, k_bf, vt);
  // 6) attn1 ∥ stat1
  k_attn_stat<<<768, 256, LDS_AS, stream>>>(q1_bf, k_bf, vt, stat_bf,
                                            l1p, l2p, l3p, aexp1, ostat1);
  // 7) f1 + fused final dot: out[m] = bf2 + sum_n relu(...)*Wf2[n]
  k_f1<<<256, 256, LDS_G128, stream>>>(aexp0, ostat0, aexp1, ostat1,
                                       query_bf, Wf1t, bf1, Wf2,
                                       (float*)d_out);
}